// Round 1
// baseline (30.053 us; speedup 1.0000x reference)
//
#include <hip/hip_runtime.h>

#define BATCH 1024
#define NANCH 3125
#define LAMB 5.0f

__device__ __forceinline__ float wave_red_f(float v) {
    #pragma unroll
    for (int o = 32; o > 0; o >>= 1) v += __shfl_down(v, o, 64);
    return v;
}
__device__ __forceinline__ int wave_red_i(int v) {
    #pragma unroll
    for (int o = 32; o > 0; o >>= 1) v += __shfl_down(v, o, 64);
    return v;
}

__global__ __launch_bounds__(256) void per_batch_kernel(
    const float* __restrict__ c_pred,    // [B,N,2]
    const float* __restrict__ r_pred,    // [B,N,4]
    const float* __restrict__ r_target,  // [B,N,4]
    const int*   __restrict__ label,     // [B,N]
    float2*      __restrict__ per_batch) // [B] -> (c_contrib, r_contrib)
{
    const int b   = blockIdx.x;
    const int tid = threadIdx.x;

    const float2* c2 = (const float2*)(c_pred   + (size_t)b * NANCH * 2);
    const float4* rp = (const float4*)(r_pred   + (size_t)b * NANCH * 4);
    const float4* rt = (const float4*)(r_target + (size_t)b * NANCH * 4);
    const int*    lb = label + (size_t)b * NANCH;

    float ce_pos_sum = 0.f, ce_neg_sum = 0.f, sl_sum = 0.f;
    int   pos_cnt = 0, neg_cnt = 0;

    for (int i = tid; i < NANCH; i += 256) {
        const int l = lb[i];
        const float2 c = c2[i];
        // log-sum-exp over the 2 logits
        const float m   = fmaxf(c.x, c.y);
        const float lse = m + log1pf(__expf(-fabsf(c.x - c.y)));
        if (l == 1) {
            pos_cnt++;
            ce_pos_sum += lse - c.y;   // -logp[...,1]
            const float4 p = rp[i];
            const float4 t = rt[i];
            float s = 0.f, d, a;
            d = p.x - t.x; a = fabsf(d); s += (a < 1.f) ? 0.5f * d * d : a - 0.5f;
            d = p.y - t.y; a = fabsf(d); s += (a < 1.f) ? 0.5f * d * d : a - 0.5f;
            d = p.z - t.z; a = fabsf(d); s += (a < 1.f) ? 0.5f * d * d : a - 0.5f;
            d = p.w - t.w; a = fabsf(d); s += (a < 1.f) ? 0.5f * d * d : a - 0.5f;
            sl_sum += s * 0.25f;       // per-anchor coord-mean
        } else if (l == 0) {
            neg_cnt++;
            ce_neg_sum += lse - c.x;   // -logp[...,0]
        }
    }

    // wave reduce (64-lane waves), then cross-wave via LDS (4 waves)
    ce_pos_sum = wave_red_f(ce_pos_sum);
    ce_neg_sum = wave_red_f(ce_neg_sum);
    sl_sum     = wave_red_f(sl_sum);
    pos_cnt    = wave_red_i(pos_cnt);
    neg_cnt    = wave_red_i(neg_cnt);

    __shared__ float s_cp[4], s_cn[4], s_sl[4];
    __shared__ int   s_pc[4], s_nc[4];
    const int wid = tid >> 6, lane = tid & 63;
    if (lane == 0) {
        s_cp[wid] = ce_pos_sum; s_cn[wid] = ce_neg_sum; s_sl[wid] = sl_sum;
        s_pc[wid] = pos_cnt;    s_nc[wid] = neg_cnt;
    }
    __syncthreads();
    if (tid == 0) {
        float cp = 0.f, cn = 0.f, sl = 0.f; int pc = 0, nc = 0;
        #pragma unroll
        for (int w = 0; w < 4; ++w) {
            cp += s_cp[w]; cn += s_cn[w]; sl += s_sl[w];
            pc += s_pc[w]; nc += s_nc[w];
        }
        const float pcf = (float)pc, ncf = (float)nc;
        const float pos_mean = (pc > 0) ? cp / fmaxf(pcf, 1.f) : 0.f;
        const float neg_mean = cn / fmaxf(ncf, 1.f);
        const float c_contrib = (pos_mean + neg_mean) * 0.5f;
        const float r_contrib = (pc > 0) ? sl / fmaxf(pcf, 1.f) : 0.f;
        per_batch[b] = make_float2(c_contrib, r_contrib);
    }
}

__global__ __launch_bounds__(256) void finalize_kernel(
    const float2* __restrict__ per_batch, // [B]
    float*        __restrict__ out)       // [3]
{
    const int tid = threadIdx.x;
    float c = 0.f, r = 0.f;
    #pragma unroll
    for (int i = tid; i < BATCH; i += 256) {
        const float2 v = per_batch[i];
        c += v.x; r += v.y;
    }
    c = wave_red_f(c);
    r = wave_red_f(r);
    __shared__ float s_c[4], s_r[4];
    const int wid = tid >> 6, lane = tid & 63;
    if (lane == 0) { s_c[wid] = c; s_r[wid] = r; }
    __syncthreads();
    if (tid == 0) {
        float cs = 0.f, rs = 0.f;
        #pragma unroll
        for (int w = 0; w < 4; ++w) { cs += s_c[w]; rs += s_r[w]; }
        const float c_loss = cs / (float)BATCH;
        const float r_loss = rs / (float)BATCH;
        out[0] = c_loss;
        out[1] = r_loss;
        out[2] = c_loss + LAMB * r_loss;
    }
}

extern "C" void kernel_launch(void* const* d_in, const int* in_sizes, int n_in,
                              void* d_out, int out_size, void* d_ws, size_t ws_size,
                              hipStream_t stream) {
    const float* c_pred   = (const float*)d_in[0];
    const float* r_pred   = (const float*)d_in[1];
    const float* r_target = (const float*)d_in[2];
    const int*   label    = (const int*)d_in[3];
    float*       out      = (float*)d_out;
    float2*      per_batch = (float2*)d_ws;   // 1024 * 8 B = 8 KiB

    per_batch_kernel<<<BATCH, 256, 0, stream>>>(c_pred, r_pred, r_target, label, per_batch);
    finalize_kernel<<<1, 256, 0, stream>>>(per_batch, out);
}